// Round 9
// baseline (285.991 us; speedup 1.0000x reference)
//
#include <hip/hip_runtime.h>

// Problem constants
#define NVEC 65536      // B*R*C = 8*16*512
#define KDIM 64
#define SDIM 512

// Output layout (flat float32)
#define Z_OFF       4194304     // NVEC*KDIM
#define LCOMMIT_OFF 4259840
#define LCODE_OFF   4259841
#define E_OFF       4259842

typedef _Float16 half8    __attribute__((ext_vector_type(8)));
typedef float    floatx16 __attribute__((ext_vector_type(16)));

// ws layout (floats): c32 [32768], cnorm [512], cbf16 [32768 floats = 65536 f16],
//                     partial [2048]
// cbf16 chunk layout (R4-verified): half index
//   (s>>5)*4096 + p*2048 + q*512 + h*256 + (s&31)*8 + j
// -> per-lane read: bb = cbf16 + j*4096 + lane*8, bh at +q*512, bl at +2048+q*512.

__global__ void vq_prep(const float* __restrict__ c_sum,
                        const float* __restrict__ c_count,
                        float* __restrict__ c32,
                        float* __restrict__ cnorm,
                        _Float16* __restrict__ cbf16) {
    int s = blockIdx.x;          // 0..511
    int k = threadIdx.x;         // 0..63
    float cnt = c_count[s];
    float inv = 1.0f / fmaxf(cnt, 0.01f);
    float x = c_sum[s * KDIM + k] * inv;
    c32[s * KDIM + k] = x;
    float sq = x * x;
    #pragma unroll
    for (int off = 32; off > 0; off >>= 1)
        sq += __shfl_down(sq, off);
    if (k == 0) cnorm[s] = sq;

    __shared__ _Float16 hb[64], lb[64];
    _Float16 hi = (_Float16)x;
    float hiF = (float)hi;
    _Float16 lo = (_Float16)(x - hiF);
    hb[k] = hi; lb[k] = lo;
    __syncthreads();
    if (k < 16) {
        int p  = k >> 3;
        int qh = k & 7;                       // q*2 + h
        int k0 = (qh >> 1) * 16 + (qh & 1) * 8;
        const _Float16* srcb = (p ? lb : hb) + k0;
        half8 v;
        #pragma unroll
        for (int j = 0; j < 8; ++j) v[j] = srcb[j];
        size_t chunk = ((size_t)(s >> 5) * 16 + p * 8 + qh) * 32 + (s & 31);
        *(half8*)(cbf16 + chunk * 8) = v;
    }
}

// R9: 2048 single-wave blocks (64 thr), M=32 vectors/wave. No __syncthreads,
// no atomics, fused 1-chain accumulator (ci in C-operand), cnorm in registers,
// straight-line 16-sub K-loop. B streamed from L2-hot global (R8-proven path).
__global__ __launch_bounds__(64, 3) void vq_main(const float* __restrict__ vecs,
                                                 const _Float16* __restrict__ cbf16,
                                                 const float* __restrict__ c32,
                                                 const float* __restrict__ cnorm,
                                                 float* __restrict__ out,
                                                 float* __restrict__ partial) {
    __shared__ int zL[32];

    const int lane = threadIdx.x;       // 0..63
    const int col  = lane & 31;
    const int h    = lane >> 5;
    const int wvec = (int)blockIdx.x * 32;

    // cnorm -> 16 registers (candidate n = j*32 + col)
    float cnr[16];
    #pragma unroll
    for (int j = 0; j < 16; ++j) cnr[j] = -0.5f * cnorm[j * 32 + col];

    // ---- A fragments (hi/lo f16) + vnorm (R4..R8-verified tree) ----
    half8 ahi[4], alo[4];
    float vnp = 0.0f;
    const float* arow = vecs + (size_t)(wvec + col) * KDIM + h * 8;
    #pragma unroll
    for (int q = 0; q < 4; ++q) {
        float4 x0 = *(const float4*)(arow + q * 16);
        float4 x1 = *(const float4*)(arow + q * 16 + 4);
        #define CVT(X, J) { float xx = (X); _Float16 hi5 = (_Float16)xx; \
                            float hf = (float)hi5; ahi[q][J] = hi5; \
                            alo[q][J] = (_Float16)(xx - hf); vnp += xx * xx; }
        CVT(x0.x, 0) CVT(x0.y, 1) CVT(x0.z, 2) CVT(x0.w, 3)
        CVT(x1.x, 4) CVT(x1.y, 5) CVT(x1.z, 6) CVT(x1.w, 7)
        #undef CVT
    }
    vnp += __shfl_xor(vnp, 32);

    // running argmax of m = -cn/2 + dot (== argmin dist; first-index ties)
    float bm[16];
    int   bi[16];
    #pragma unroll
    for (int r = 0; r < 16; ++r) { bm[r] = -3.4e38f; bi[r] = 0; }

    #pragma unroll
    for (int j = 0; j < 16; ++j) {      // j = t*4 + sub: straight-line 16 subs
        const _Float16* bb = cbf16 + (size_t)j * 4096 + lane * 8;
        float ci = cnr[j];
        floatx16 a;
        #pragma unroll
        for (int r = 0; r < 16; ++r) a[r] = ci;   // ci rides the C-operand
        #pragma unroll
        for (int q = 0; q < 4; ++q) {
            half8 bh = *(const half8*)(bb + q * 512);          // global, L2-hot
            half8 bl = *(const half8*)(bb + 2048 + q * 512);
            a = __builtin_amdgcn_mfma_f32_32x32x16_f16(ahi[q], bh, a, 0, 0, 0);
            a = __builtin_amdgcn_mfma_f32_32x32x16_f16(alo[q], bh, a, 0, 0, 0);
            a = __builtin_amdgcn_mfma_f32_32x32x16_f16(ahi[q], bl, a, 0, 0, 0);
        }
        int n = j * 32 + col;
        #pragma unroll
        for (int r = 0; r < 16; ++r) {
            if (a[r] > bm[r]) { bm[r] = a[r]; bi[r] = n; }   // strict >, incr. n
        }
    }

    // ---- cross-lane argmax per row (32 cols; xor<=16 stays within h) ----
    #pragma unroll
    for (int r = 0; r < 16; ++r) {
        float v = bm[r]; int i = bi[r];
        #pragma unroll
        for (int off = 16; off > 0; off >>= 1) {
            float ov = __shfl_xor(v, off);
            int   oi = __shfl_xor(i, off);
            if (ov > v || (ov == v && oi < i)) { v = ov; i = oi; }
        }
        bm[r] = v; bi[r] = i;
    }

    // vnorm per output row via shuffle (all lanes participate — no divergence)
    float vnr[16];
    #pragma unroll
    for (int r = 0; r < 16; ++r) {
        int row = (r & 3) + 8 * (r >> 2) + 4 * h;   // C/D row map (verified)
        vnr[r] = __shfl(vnp, row);                  // vnp of lane 'row' (h=0 copy)
    }

    float esum = 0.0f;
    if (col == 0) {
        #pragma unroll
        for (int r = 0; r < 16; ++r) {
            int row = (r & 3) + 8 * (r >> 2) + 4 * h;
            int vid = wvec + row;
            float err = fmaxf(vnr[r] - 2.0f * bm[r], 0.0f);
            out[Z_OFF + vid] = (float)bi[r];
            out[E_OFF + vid] = err;
            zL[row] = bi[r];
            esum += err;
        }
    }
    // combine the two col==0 partials (lanes 0 and 32), store per-block partial
    esum += __shfl_xor(esum, 32);
    if (lane == 0) partial[blockIdx.x] = esum;

    // ---- vecs_hat gather from c32 (L2-hot), coalesced float4 stores ----
    #pragma unroll
    for (int it = 0; it < 8; ++it) {
        int row = it * 4 + (lane >> 4);
        int c4  = lane & 15;
        int z   = zL[row];
        float4 val = *(const float4*)(c32 + (size_t)z * KDIM + c4 * 4);
        *(float4*)(out + (size_t)(wvec + row) * KDIM + c4 * 4) = val;
    }
}

// Final scalar reduce: 2048 partials -> l_commit; also writes l_codebook = 0.
__global__ void vq_reduce(const float* __restrict__ partial,
                          float* __restrict__ out) {
    __shared__ float ws[4];
    int tx = threadIdx.x;
    float s = 0.0f;
    #pragma unroll
    for (int j = 0; j < 8; ++j) s += partial[tx + j * 256];
    #pragma unroll
    for (int off = 32; off > 0; off >>= 1) s += __shfl_down(s, off);
    if ((tx & 63) == 0) ws[tx >> 6] = s;
    __syncthreads();
    if (tx == 0) {
        float tot = ws[0] + ws[1] + ws[2] + ws[3];
        out[LCOMMIT_OFF] = tot * (1.0f / (float)NVEC);
        out[LCODE_OFF]   = 0.0f;
    }
}

extern "C" void kernel_launch(void* const* d_in, const int* in_sizes, int n_in,
                              void* d_out, int out_size, void* d_ws, size_t ws_size,
                              hipStream_t stream) {
    const float* vecs    = (const float*)d_in[0];  // [8,16,512,64]
    const float* c_sum   = (const float*)d_in[1];  // [512,64]
    const float* c_count = (const float*)d_in[2];  // [512]
    float* out = (float*)d_out;

    float*    c32     = (float*)d_ws;                    // [32768]
    float*    cnorm   = c32 + SDIM * KDIM;               // [512]
    _Float16* cbf16   = (_Float16*)(cnorm + SDIM);       // [65536 halfs]
    float*    partial = (float*)(cbf16 + SDIM * KDIM * 2); // [2048]

    vq_prep<<<SDIM, KDIM, 0, stream>>>(c_sum, c_count, c32, cnorm, cbf16);
    vq_main<<<NVEC / 32, 64, 0, stream>>>(vecs, cbf16, c32, cnorm, out, partial);
    vq_reduce<<<1, 256, 0, stream>>>(partial, out);
}